// Round 5
// baseline (583.954 us; speedup 1.0000x reference)
//
#include <hip/hip_runtime.h>

namespace {

constexpr int NR = 8192;
constexpr int DD = 512;
constexpr int NSPLIT = 4;
constexpr int KVLEN = NR / NSPLIT;   // 2048
constexpr int KT = 64;               // kv tile (doubled: amortize per-tile fixed cost)
constexpr int NT = KVLEN / KT;       // 32 tiles
constexpr int QB = 64;               // q rows per block
constexpr float SCALE = 0.04419417382415922f;  // 1/sqrt(512)
constexpr float THR = 5.0f;          // defer-max threshold

typedef __bf16 bf16x8 __attribute__((ext_vector_type(8)));
typedef __bf16 bf16x4 __attribute__((ext_vector_type(4)));
typedef float  f32x16 __attribute__((ext_vector_type(16)));

__device__ __forceinline__ f32x16 mfma(bf16x8 a, bf16x8 b, f32x16 c) {
    return __builtin_amdgcn_mfma_f32_32x32x16_bf16(a, b, c, 0, 0, 0);
}

// ---------------- fp32 -> bf16 cast ----------------
__global__ void __launch_bounds__(256)
cast_kernel(const float* __restrict__ in, __bf16* __restrict__ out, int n8) {
    int i = blockIdx.x * 256 + threadIdx.x;
    if (i >= n8) return;
    const float4* p = (const float4*)(in + (size_t)i * 8);
    float4 v0 = p[0], v1 = p[1];
    bf16x8 o;
    o[0] = (__bf16)v0.x; o[1] = (__bf16)v0.y; o[2] = (__bf16)v0.z; o[3] = (__bf16)v0.w;
    o[4] = (__bf16)v1.x; o[5] = (__bf16)v1.y; o[6] = (__bf16)v1.z; o[7] = (__bf16)v1.w;
    *(bf16x8*)(out + (size_t)i * 8) = o;
}

// ---------------- GEMM C = A * B^T  (M=8192, N=512, K=512) ----------------
template<bool FINAL>
__global__ void __launch_bounds__(256, 2)
gemm_kernel(const __bf16* __restrict__ A, const __bf16* __restrict__ B0,
            const __bf16* __restrict__ B1, const __bf16* __restrict__ B2,
            __bf16* __restrict__ C0, __bf16* __restrict__ C1, __bf16* __restrict__ C2,
            const float* __restrict__ bias, float* __restrict__ Cf)
{
    const __bf16* B = B0;
    __bf16* Cb = C0;
    if (!FINAL) {
        if (blockIdx.y == 1)      { B = B1; Cb = C1; }
        else if (blockIdx.y == 2) { B = B2; Cb = C2; }
    }
    __shared__ __bf16 As[128][72];
    __shared__ __bf16 Bs[128][72];
    const int t = threadIdx.x;
    const int w = t >> 6, lane = t & 63, lo = lane & 31, hi = lane >> 5;
    const int wm = w >> 1, wn = w & 1;
    const int bm = (blockIdx.x >> 2) * 128;
    const int bn = (blockIdx.x & 3) * 128;

    f32x16 acc[2][2];
    #pragma unroll
    for (int a = 0; a < 2; ++a)
        #pragma unroll
        for (int b = 0; b < 2; ++b)
            #pragma unroll
            for (int r = 0; r < 16; ++r) acc[a][b][r] = 0.f;

    for (int k0 = 0; k0 < DD; k0 += 64) {
        __syncthreads();
        #pragma unroll
        for (int pp = 0; pp < 2; ++pp) {
            int r = pp * 64 + (t >> 2), c = (t & 3) * 16;
            *(bf16x8*)&As[r][c]     = *(const bf16x8*)(A + (size_t)(bm + r) * DD + k0 + c);
            *(bf16x8*)&As[r][c + 8] = *(const bf16x8*)(A + (size_t)(bm + r) * DD + k0 + c + 8);
            *(bf16x8*)&Bs[r][c]     = *(const bf16x8*)(B + (size_t)(bn + r) * DD + k0 + c);
            *(bf16x8*)&Bs[r][c + 8] = *(const bf16x8*)(B + (size_t)(bn + r) * DD + k0 + c + 8);
        }
        __syncthreads();
        #pragma unroll
        for (int ks = 0; ks < 4; ++ks) {
            bf16x8 a0 = *(const bf16x8*)&As[wm * 64 + lo][ks * 16 + hi * 8];
            bf16x8 a1 = *(const bf16x8*)&As[wm * 64 + 32 + lo][ks * 16 + hi * 8];
            bf16x8 b0 = *(const bf16x8*)&Bs[wn * 64 + lo][ks * 16 + hi * 8];
            bf16x8 b1 = *(const bf16x8*)&Bs[wn * 64 + 32 + lo][ks * 16 + hi * 8];
            acc[0][0] = mfma(a0, b0, acc[0][0]);
            acc[0][1] = mfma(a0, b1, acc[0][1]);
            acc[1][0] = mfma(a1, b0, acc[1][0]);
            acc[1][1] = mfma(a1, b1, acc[1][1]);
        }
    }
    #pragma unroll
    for (int mi = 0; mi < 2; ++mi)
        #pragma unroll
        for (int ni = 0; ni < 2; ++ni) {
            int col = bn + wn * 64 + ni * 32 + lo;
            float bv = 0.f;
            if (FINAL) bv = bias[col];
            #pragma unroll
            for (int r = 0; r < 16; ++r) {
                int row = bm + wm * 64 + mi * 32 + (r & 3) + 8 * (r >> 2) + 4 * hi;
                if (FINAL) Cf[(size_t)row * DD + col] = acc[mi][ni][r] + bv;
                else       Cb[(size_t)row * DD + col] = (__bf16)acc[mi][ni][r];
            }
        }
}

// ---------------- transpose V[8192][512] -> Vt[512][8192] ----------------
__global__ void __launch_bounds__(256)
transpose_kernel(const __bf16* __restrict__ V, __bf16* __restrict__ Vt) {
    __shared__ __bf16 tile[64][72];
    const int t = threadIdx.x;
    const int rb = blockIdx.x * 64;   // n
    const int cb = blockIdx.y * 64;   // d
    #pragma unroll
    for (int pp = 0; pp < 2; ++pp) {
        int r = pp * 32 + (t >> 3), c = (t & 7) * 8;
        *(bf16x8*)&tile[r][c] = *(const bf16x8*)(V + (size_t)(rb + r) * DD + cb + c);
    }
    __syncthreads();
    #pragma unroll
    for (int pp = 0; pp < 2; ++pp) {
        int dd = pp * 32 + (t >> 3), co = (t & 7) * 8;
        bf16x8 o;
        #pragma unroll
        for (int j = 0; j < 8; ++j) o[j] = tile[co + j][dd];
        *(bf16x8*)(Vt + (size_t)(cb + dd) * NR + rb + co) = o;
    }
}

// ---------------- flash attention, KT=64, direct-L2 K/V, 2 barriers/tile ----------------
// grid = (128 q-blocks, 4 kv-splits); 256 threads = 4 waves; ~46.6 KB LDS -> 2 blocks/CU.
// Wave w: Q[64 q][d in w*128 .. +128) in regs; O cols = w*128 + h*64 + ni*32 + lo.
// QK^T swapped (mfma(K,Q)), computed in two kv-halves reusing the same accumulators
// (flat register pressure). adj prefetched one tile (64 kv) ahead into registers.
__global__ void __launch_bounds__(256, 2)
flash_kernel(const __bf16* __restrict__ Qg, const __bf16* __restrict__ Kg,
             const __bf16* __restrict__ Vt, const int* __restrict__ adj,
             __bf16* __restrict__ Opart, float* __restrict__ lse)
{
    __shared__ __bf16 Sp[4][QB][KT + 8];   // per-wave score partials (d-split)
    __shared__ __bf16 Pl[QB][KT + 8];      // post-softmax P
    __shared__ float  fl[QB];              // per-tile rescale factors
    __shared__ float  ll[QB];              // final l
    __shared__ int    flg[4];              // per-wave "any row needs rescale"

    const int t = threadIdx.x;
    const int w = t >> 6, lane = t & 63, lo = lane & 31, hi = lane >> 5;
    const int qblk = blockIdx.x * QB;
    const int split = blockIdx.y;
    const int kv0 = split * KVLEN;

    // Q fragments: rows qblk + mi*32 + lo ; cols w*128 + ks*16 + hi*8
    bf16x8 qa[2][8];
    #pragma unroll
    for (int mi = 0; mi < 2; ++mi)
        #pragma unroll
        for (int ks = 0; ks < 8; ++ks)
            qa[mi][ks] = *(const bf16x8*)(Qg + (size_t)(qblk + mi * 32 + lo) * DD + w * 128 + ks * 16 + hi * 8);

    f32x16 O[2][2][2];  // [h][mi][ni]
    #pragma unroll
    for (int h = 0; h < 2; ++h)
        #pragma unroll
        for (int a = 0; a < 2; ++a)
            #pragma unroll
            for (int b = 0; b < 2; ++b)
                #pragma unroll
                for (int r = 0; r < 16; ++r) O[h][a][b][r] = 0.f;

    // per-lane global bases
    const __bf16* Kl = Kg + (size_t)(kv0 + lo) * DD + w * 128 + hi * 8;
    const __bf16* Vbase = Vt + (size_t)(w * 128 + lo) * NR + kv0 + hi * 8;

    const int qo = w * 16 + (lane >> 2);   // softmax-owned row
    const int c16 = (lane & 3) * 16;       // softmax-owned kv chunk (16 wide)
    const int* adjp = adj + (size_t)(qblk + qo) * NR + kv0 + c16;
    int4 aA = *(const int4*)adjp;          // prefetched adj (tile 0)
    int4 aB = *(const int4*)(adjp + 4);
    int4 aC = *(const int4*)(adjp + 8);
    int4 aD = *(const int4*)(adjp + 12);

    float m_run = -1e30f, l_run = 0.f;

    for (int tl = 0; tl < NT; ++tl) {
        // ---- QK^T partial (swapped: St[kv][q]) over this wave's 128-d slice ----
        // two kv-halves of 32, reusing the same accumulators
        #pragma unroll
        for (int hh = 0; hh < 2; ++hh) {
            f32x16 St0, St1;
            #pragma unroll
            for (int r = 0; r < 16; ++r) { St0[r] = 0.f; St1[r] = 0.f; }
            #pragma unroll
            for (int ks = 0; ks < 8; ++ks) {
                bf16x8 kb = *(const bf16x8*)(Kl + (size_t)hh * 32 * DD + ks * 16);
                St0 = mfma(kb, qa[0][ks], St0);
                St1 = mfma(kb, qa[1][ks], St1);
            }
            #pragma unroll
            for (int g = 0; g < 4; ++g) {
                bf16x4 v0, v1;
                #pragma unroll
                for (int j = 0; j < 4; ++j) { v0[j] = (__bf16)St0[4 * g + j]; v1[j] = (__bf16)St1[4 * g + j]; }
                *(bf16x4*)&Sp[w][lo][hh * 32 + 8 * g + 4 * hi]      = v0;
                *(bf16x4*)&Sp[w][32 + lo][hh * 32 + 8 * g + 4 * hi] = v1;
            }
        }
        Kl += (size_t)KT * DD;
        __syncthreads();   // B1

        // ---- masked online softmax (4 lanes per row, 16 kv each), defer-max ----
        {
            bf16x8 pp[4][2];
            #pragma unroll
            for (int ww = 0; ww < 4; ++ww) {
                pp[ww][0] = *(const bf16x8*)&Sp[ww][qo][c16];
                pp[ww][1] = *(const bf16x8*)&Sp[ww][qo][c16 + 8];
            }
            int am[16] = {aA.x, aA.y, aA.z, aA.w, aB.x, aB.y, aB.z, aB.w,
                          aC.x, aC.y, aC.z, aC.w, aD.x, aD.y, aD.z, aD.w};
            float s[16];
            #pragma unroll
            for (int i = 0; i < 16; ++i) {
                int ch = i >> 3, e = i & 7;
                float v = ((float)pp[0][ch][e] + (float)pp[1][ch][e] +
                           (float)pp[2][ch][e] + (float)pp[3][ch][e]) * SCALE;
                s[i] = (am[i] != 0) ? v : -1e30f;
            }
            float mx = s[0];
            #pragma unroll
            for (int i = 1; i < 16; ++i) mx = fmaxf(mx, s[i]);
            mx = fmaxf(mx, __shfl_xor(mx, 1));
            mx = fmaxf(mx, __shfl_xor(mx, 2));
            bool need = mx > m_run + THR;
            float m_new = need ? mx : m_run;
            float f = need ? __expf(m_run - m_new) : 1.f;
            float lsum = 0.f;
            bf16x8 pb0, pb1;
            #pragma unroll
            for (int i = 0; i < 16; ++i) {
                float pv = __expf(s[i] - m_new);
                lsum += pv;
                if (i < 8) pb0[i] = (__bf16)pv; else pb1[i - 8] = (__bf16)pv;
            }
            lsum += __shfl_xor(lsum, 1);
            lsum += __shfl_xor(lsum, 2);
            l_run = l_run * f + lsum;
            m_run = m_new;
            *(bf16x8*)&Pl[qo][c16]     = pb0;
            *(bf16x8*)&Pl[qo][c16 + 8] = pb1;
            if ((lane & 3) == 0) fl[qo] = f;
            unsigned long long bal = __ballot(need);
            if (lane == 0) flg[w] = (bal != 0ull) ? 1 : 0;
            // prefetch adj for next tile (full tile of cover)
            int nxt = (tl + 1 < NT) ? (tl + 1) * KT : 0;
            aA = *(const int4*)(adjp + nxt);
            aB = *(const int4*)(adjp + nxt + 4);
            aC = *(const int4*)(adjp + nxt + 8);
            aD = *(const int4*)(adjp + nxt + 12);
        }
        __syncthreads();   // B2

        // ---- rescale O only when some row's max grew (block-uniform branch) ----
        if (flg[0] | flg[1] | flg[2] | flg[3]) {
            #pragma unroll
            for (int mi = 0; mi < 2; ++mi)
                #pragma unroll
                for (int g = 0; g < 4; ++g) {
                    float4 fv = *(const float4*)&fl[mi * 32 + 8 * g + 4 * hi];
                    #pragma unroll
                    for (int j = 0; j < 4; ++j) {
                        float fac = (&fv.x)[j];
                        #pragma unroll
                        for (int h = 0; h < 2; ++h)
                            #pragma unroll
                            for (int ni = 0; ni < 2; ++ni)
                                O[h][mi][ni][g * 4 + j] *= fac;
                    }
                }
        }
        // ---- PV: P frags from LDS, V frags direct from L2 ----
        bf16x8 pa[2][4];
        #pragma unroll
        for (int mi = 0; mi < 2; ++mi)
            #pragma unroll
            for (int ks = 0; ks < 4; ++ks)
                pa[mi][ks] = *(const bf16x8*)&Pl[mi * 32 + lo][ks * 16 + hi * 8];
        const int vofs = tl * KT;
        #pragma unroll
        for (int h = 0; h < 2; ++h)
            #pragma unroll
            for (int ni = 0; ni < 2; ++ni) {
                const __bf16* vp = Vbase + (size_t)(h * 64 + ni * 32) * NR + vofs;
                #pragma unroll
                for (int ks = 0; ks < 4; ++ks) {
                    bf16x8 vb = *(const bf16x8*)(vp + ks * 16);
                    O[h][0][ni] = mfma(pa[0][ks], vb, O[h][0][ni]);
                    O[h][1][ni] = mfma(pa[1][ks], vb, O[h][1][ni]);
                }
            }
    }
    // ---- epilogue ----
    if ((lane & 3) == 0) {
        ll[qo] = l_run;
        lse[(size_t)split * NR + qblk + qo] = m_run + __logf(l_run);
    }
    __syncthreads();
    #pragma unroll
    for (int mi = 0; mi < 2; ++mi)
        #pragma unroll
        for (int g = 0; g < 4; ++g) {
            float4 lv = *(const float4*)&ll[mi * 32 + 8 * g + 4 * hi];
            #pragma unroll
            for (int j = 0; j < 4; ++j) {
                float inv = 1.f / (&lv.x)[j];
                int row = qblk + mi * 32 + 8 * g + 4 * hi + j;
                #pragma unroll
                for (int h = 0; h < 2; ++h)
                    #pragma unroll
                    for (int ni = 0; ni < 2; ++ni) {
                        int col = w * 128 + h * 64 + ni * 32 + lo;
                        Opart[(size_t)split * NR * DD + (size_t)row * DD + col] =
                            (__bf16)(O[h][mi][ni][g * 4 + j] * inv);
                    }
            }
        }
}

// ---------------- merge kv-splits ----------------
__global__ void __launch_bounds__(256)
merge_kernel(const __bf16* __restrict__ Opart, const float* __restrict__ lse,
             __bf16* __restrict__ attn)
{
    int idx = blockIdx.x * 256 + threadIdx.x;
    int q = idx >> 6;
    int c = (idx & 63) * 8;
    float l0 = lse[q], l1 = lse[NR + q], l2 = lse[2 * NR + q], l3 = lse[3 * NR + q];
    float M = fmaxf(fmaxf(l0, l1), fmaxf(l2, l3));
    float w0 = __expf(l0 - M), w1 = __expf(l1 - M), w2 = __expf(l2 - M), w3 = __expf(l3 - M);
    float Winv = 1.f / (w0 + w1 + w2 + w3);
    const size_t base = (size_t)q * DD + c;
    const size_t stride = (size_t)NR * DD;
    bf16x8 o0 = *(const bf16x8*)(Opart + base);
    bf16x8 o1 = *(const bf16x8*)(Opart + stride + base);
    bf16x8 o2 = *(const bf16x8*)(Opart + 2 * stride + base);
    bf16x8 o3 = *(const bf16x8*)(Opart + 3 * stride + base);
    bf16x8 o;
    #pragma unroll
    for (int i = 0; i < 8; ++i)
        o[i] = (__bf16)((w0 * (float)o0[i] + w1 * (float)o1[i] +
                         w2 * (float)o2[i] + w3 * (float)o3[i]) * Winv);
    *(bf16x8*)(attn + base) = o;
}

} // namespace

extern "C" void kernel_launch(void* const* d_in, const int* in_sizes, int n_in,
                              void* d_out, int out_size, void* d_ws, size_t ws_size,
                              hipStream_t stream)
{
    (void)in_sizes; (void)n_in; (void)out_size; (void)ws_size;
    const float* X  = (const float*)d_in[0];
    const int*   adj = (const int*)d_in[1];
    const float* Wq = (const float*)d_in[2];
    const float* Wk = (const float*)d_in[3];
    const float* Wv = (const float*)d_in[4];
    const float* Wo = (const float*)d_in[5];
    const float* bo = (const float*)d_in[6];
    float* out = (float*)d_out;

    char* ws = (char*)d_ws;
    __bf16* Xb   = (__bf16*)(ws + 0);
    __bf16* Att  = (__bf16*)(ws + 0);        // reuses Xb (dead after QKV gemm)
    __bf16* Wqb  = (__bf16*)(ws + 8388608);
    __bf16* Wkb  = (__bf16*)(ws + 8912896);
    __bf16* Wvb  = (__bf16*)(ws + 9437184);
    __bf16* Wob  = (__bf16*)(ws + 9961472);
    __bf16* Qb   = (__bf16*)(ws + 10485760);
    __bf16* Kb   = (__bf16*)(ws + 18874368);
    __bf16* Vb   = (__bf16*)(ws + 27262976);
    __bf16* Vtb  = (__bf16*)(ws + 35651584);
    __bf16* Op   = (__bf16*)(ws + 44040192);
    float*  lseb = (float*)(ws + 77594624);

    cast_kernel<<<2048, 256, 0, stream>>>(X,  Xb,  NR * DD / 8);
    cast_kernel<<<128,  256, 0, stream>>>(Wq, Wqb, DD * DD / 8);
    cast_kernel<<<128,  256, 0, stream>>>(Wk, Wkb, DD * DD / 8);
    cast_kernel<<<128,  256, 0, stream>>>(Wv, Wvb, DD * DD / 8);
    cast_kernel<<<128,  256, 0, stream>>>(Wo, Wob, DD * DD / 8);

    gemm_kernel<false><<<dim3(256, 3), 256, 0, stream>>>(Xb, Wqb, Wkb, Wvb,
                                                         Qb, Kb, Vb, nullptr, nullptr);
    transpose_kernel<<<dim3(128, 8), 256, 0, stream>>>(Vb, Vtb);
    flash_kernel<<<dim3(128, NSPLIT), 256, 0, stream>>>(Qb, Kb, Vtb, adj, Op, lseb);
    merge_kernel<<<2048, 256, 0, stream>>>(Op, lseb, Att);
    gemm_kernel<true><<<dim3(256, 1), 256, 0, stream>>>(Att, Wob, nullptr, nullptr,
                                                        nullptr, nullptr, nullptr, bo, out);
}

// Round 6
// 421.735 us; speedup vs baseline: 1.3846x; 1.3846x over previous
//
#include <hip/hip_runtime.h>

namespace {

constexpr int NR = 8192;
constexpr int DD = 512;
constexpr int LDK = 528;             // padded K row stride (breaks 1KB channel alias)
constexpr int LDV = 8208;            // padded Vt row stride (breaks 16KB channel alias)
constexpr int NSPLIT = 4;
constexpr int KVLEN = NR / NSPLIT;   // 2048
constexpr int KT = 32;               // kv tile
constexpr int NT = KVLEN / KT;       // 64 tiles
constexpr int QB = 64;               // q rows per block
constexpr float SCALE = 0.04419417382415922f;  // 1/sqrt(512)
constexpr float THR = 5.0f;          // defer-max threshold

typedef __bf16 bf16x8 __attribute__((ext_vector_type(8)));
typedef __bf16 bf16x4 __attribute__((ext_vector_type(4)));
typedef float  f32x16 __attribute__((ext_vector_type(16)));

__device__ __forceinline__ f32x16 mfma(bf16x8 a, bf16x8 b, f32x16 c) {
    return __builtin_amdgcn_mfma_f32_32x32x16_bf16(a, b, c, 0, 0, 0);
}

// ---------------- fp32 -> bf16 cast ----------------
__global__ void __launch_bounds__(256)
cast_kernel(const float* __restrict__ in, __bf16* __restrict__ out, int n8) {
    int i = blockIdx.x * 256 + threadIdx.x;
    if (i >= n8) return;
    const float4* p = (const float4*)(in + (size_t)i * 8);
    float4 v0 = p[0], v1 = p[1];
    bf16x8 o;
    o[0] = (__bf16)v0.x; o[1] = (__bf16)v0.y; o[2] = (__bf16)v0.z; o[3] = (__bf16)v0.w;
    o[4] = (__bf16)v1.x; o[5] = (__bf16)v1.y; o[6] = (__bf16)v1.z; o[7] = (__bf16)v1.w;
    *(bf16x8*)(out + (size_t)i * 8) = o;
}

// ---------------- GEMM C = A * B^T  (M=8192, N=512, K=512) ----------------
// FINAL=false: grid.y selects (Wq->Q ld512, Wk->K ld LDK, Wv->V ld512), bf16 out.
template<bool FINAL>
__global__ void __launch_bounds__(256, 2)
gemm_kernel(const __bf16* __restrict__ A, const __bf16* __restrict__ B0,
            const __bf16* __restrict__ B1, const __bf16* __restrict__ B2,
            __bf16* __restrict__ C0, __bf16* __restrict__ C1, __bf16* __restrict__ C2,
            const float* __restrict__ bias, float* __restrict__ Cf)
{
    const __bf16* B = B0;
    __bf16* Cb = C0;
    int ldc = DD;
    if (!FINAL) {
        if (blockIdx.y == 1)      { B = B1; Cb = C1; ldc = LDK; }
        else if (blockIdx.y == 2) { B = B2; Cb = C2; }
    }
    __shared__ __bf16 As[128][72];
    __shared__ __bf16 Bs[128][72];
    const int t = threadIdx.x;
    const int w = t >> 6, lane = t & 63, lo = lane & 31, hi = lane >> 5;
    const int wm = w >> 1, wn = w & 1;
    const int bm = (blockIdx.x >> 2) * 128;
    const int bn = (blockIdx.x & 3) * 128;

    f32x16 acc[2][2];
    #pragma unroll
    for (int a = 0; a < 2; ++a)
        #pragma unroll
        for (int b = 0; b < 2; ++b)
            #pragma unroll
            for (int r = 0; r < 16; ++r) acc[a][b][r] = 0.f;

    for (int k0 = 0; k0 < DD; k0 += 64) {
        __syncthreads();
        #pragma unroll
        for (int pp = 0; pp < 2; ++pp) {
            int r = pp * 64 + (t >> 2), c = (t & 3) * 16;
            *(bf16x8*)&As[r][c]     = *(const bf16x8*)(A + (size_t)(bm + r) * DD + k0 + c);
            *(bf16x8*)&As[r][c + 8] = *(const bf16x8*)(A + (size_t)(bm + r) * DD + k0 + c + 8);
            *(bf16x8*)&Bs[r][c]     = *(const bf16x8*)(B + (size_t)(bn + r) * DD + k0 + c);
            *(bf16x8*)&Bs[r][c + 8] = *(const bf16x8*)(B + (size_t)(bn + r) * DD + k0 + c + 8);
        }
        __syncthreads();
        #pragma unroll
        for (int ks = 0; ks < 4; ++ks) {
            bf16x8 a0 = *(const bf16x8*)&As[wm * 64 + lo][ks * 16 + hi * 8];
            bf16x8 a1 = *(const bf16x8*)&As[wm * 64 + 32 + lo][ks * 16 + hi * 8];
            bf16x8 b0 = *(const bf16x8*)&Bs[wn * 64 + lo][ks * 16 + hi * 8];
            bf16x8 b1 = *(const bf16x8*)&Bs[wn * 64 + 32 + lo][ks * 16 + hi * 8];
            acc[0][0] = mfma(a0, b0, acc[0][0]);
            acc[0][1] = mfma(a0, b1, acc[0][1]);
            acc[1][0] = mfma(a1, b0, acc[1][0]);
            acc[1][1] = mfma(a1, b1, acc[1][1]);
        }
    }
    #pragma unroll
    for (int mi = 0; mi < 2; ++mi)
        #pragma unroll
        for (int ni = 0; ni < 2; ++ni) {
            int col = bn + wn * 64 + ni * 32 + lo;
            float bv = 0.f;
            if (FINAL) bv = bias[col];
            #pragma unroll
            for (int r = 0; r < 16; ++r) {
                int row = bm + wm * 64 + mi * 32 + (r & 3) + 8 * (r >> 2) + 4 * hi;
                if (FINAL) Cf[(size_t)row * DD + col] = acc[mi][ni][r] + bv;
                else       Cb[(size_t)row * ldc + col] = (__bf16)acc[mi][ni][r];
            }
        }
}

// ---------------- transpose V[8192][512] -> Vt[512][LDV] (padded) ----------------
__global__ void __launch_bounds__(256)
transpose_kernel(const __bf16* __restrict__ V, __bf16* __restrict__ Vt) {
    __shared__ __bf16 tile[64][72];
    const int t = threadIdx.x;
    const int rb = blockIdx.x * 64;   // n
    const int cb = blockIdx.y * 64;   // d
    #pragma unroll
    for (int pp = 0; pp < 2; ++pp) {
        int r = pp * 32 + (t >> 3), c = (t & 7) * 8;
        *(bf16x8*)&tile[r][c] = *(const bf16x8*)(V + (size_t)(rb + r) * DD + cb + c);
    }
    __syncthreads();
    #pragma unroll
    for (int pp = 0; pp < 2; ++pp) {
        int dd = pp * 32 + (t >> 3), co = (t & 7) * 8;
        bf16x8 o;
        #pragma unroll
        for (int j = 0; j < 8; ++j) o[j] = tile[co + j][dd];
        *(bf16x8*)(Vt + (size_t)(cb + dd) * LDV + rb + co) = o;
    }
}

// ---------------- flash attention, padded layouts + XCD-locality swizzle ----------------
// 1-D grid of 512 blocks; xcd = bid&7 selects (split = xcd>>1) so each kv-split's
// K+Vt (~4 MB) stays resident in one XCD pair's L2. K rows at 1056 B stride and Vt
// rows at 16416 B stride de-alias L2 slices / HBM channels. adj prefetched 2 tiles ahead.
__global__ void __launch_bounds__(256, 2)
flash_kernel(const __bf16* __restrict__ Qg, const __bf16* __restrict__ Kg,
             const __bf16* __restrict__ Vt, const int* __restrict__ adj,
             __bf16* __restrict__ Opart, float* __restrict__ lse)
{
    __shared__ __bf16 Sp[4][QB][40];   // per-wave score partials (d-split)
    __shared__ __bf16 Pl[QB][40];      // post-softmax P
    __shared__ float  fl[QB];          // per-tile rescale factors
    __shared__ float  ll[QB];          // final l
    __shared__ int    flg[4];          // per-wave "any row needs rescale"

    const int t = threadIdx.x;
    const int w = t >> 6, lane = t & 63, lo = lane & 31, hi = lane >> 5;
    const int bid = blockIdx.x;
    const int xcd = bid & 7;
    const int j8 = bid >> 3;                     // 0..63
    const int split = xcd >> 1;                  // 2 XCDs per split
    const int qblk = (((xcd & 1) << 6) | j8) * QB;
    const int kv0 = split * KVLEN;

    // Q fragments: rows qblk + mi*32 + lo ; cols w*128 + ks*16 + hi*8
    bf16x8 qa[2][8];
    #pragma unroll
    for (int mi = 0; mi < 2; ++mi)
        #pragma unroll
        for (int ks = 0; ks < 8; ++ks)
            qa[mi][ks] = *(const bf16x8*)(Qg + (size_t)(qblk + mi * 32 + lo) * DD + w * 128 + ks * 16 + hi * 8);

    f32x16 O[2][2][2];  // [h][mi][ni]
    #pragma unroll
    for (int h = 0; h < 2; ++h)
        #pragma unroll
        for (int a = 0; a < 2; ++a)
            #pragma unroll
            for (int b = 0; b < 2; ++b)
                #pragma unroll
                for (int r = 0; r < 16; ++r) O[h][a][b][r] = 0.f;

    // per-lane global bases (padded strides)
    const __bf16* Kl = Kg + (size_t)(kv0 + lo) * LDK + w * 128 + hi * 8;
    const __bf16* Vbase = Vt + (size_t)(w * 128 + lo) * LDV + kv0 + hi * 8;

    const int qo = w * 16 + (lane >> 2);   // softmax-owned row
    const int c8 = (lane & 3) * 8;         // softmax-owned kv chunk
    const int* adjp = adj + (size_t)(qblk + qo) * NR + kv0 + c8;
    int4 aA = *(const int4*)adjp;               // tile 0
    int4 aB = *(const int4*)(adjp + 4);
    int4 bA = *(const int4*)(adjp + KT);        // tile 1
    int4 bB = *(const int4*)(adjp + KT + 4);

    float m_run = -1e30f, l_run = 0.f;

    for (int tl = 0; tl < NT; ++tl) {
        // ---- QK^T partial (swapped: St[kv][q]) over this wave's 128-d slice ----
        f32x16 St0, St1;
        #pragma unroll
        for (int r = 0; r < 16; ++r) { St0[r] = 0.f; St1[r] = 0.f; }
        #pragma unroll
        for (int ks = 0; ks < 8; ++ks) {
            bf16x8 kb = *(const bf16x8*)(Kl + ks * 16);
            St0 = mfma(kb, qa[0][ks], St0);
            St1 = mfma(kb, qa[1][ks], St1);
        }
        Kl += (size_t)KT * LDK;
        #pragma unroll
        for (int g = 0; g < 4; ++g) {
            bf16x4 v0, v1;
            #pragma unroll
            for (int jj = 0; jj < 4; ++jj) { v0[jj] = (__bf16)St0[4 * g + jj]; v1[jj] = (__bf16)St1[4 * g + jj]; }
            *(bf16x4*)&Sp[w][lo][8 * g + 4 * hi]      = v0;
            *(bf16x4*)&Sp[w][32 + lo][8 * g + 4 * hi] = v1;
        }
        __syncthreads();   // B1
        // ---- masked online softmax (4 lanes per row), defer-max ----
        {
            bf16x8 p0 = *(const bf16x8*)&Sp[0][qo][c8];
            bf16x8 p1 = *(const bf16x8*)&Sp[1][qo][c8];
            bf16x8 p2 = *(const bf16x8*)&Sp[2][qo][c8];
            bf16x8 p3 = *(const bf16x8*)&Sp[3][qo][c8];
            int am[8] = {aA.x, aA.y, aA.z, aA.w, aB.x, aB.y, aB.z, aB.w};
            float s[8];
            #pragma unroll
            for (int i = 0; i < 8; ++i) {
                float v = ((float)p0[i] + (float)p1[i] + (float)p2[i] + (float)p3[i]) * SCALE;
                s[i] = (am[i] != 0) ? v : -1e30f;
            }
            float mx = s[0];
            #pragma unroll
            for (int i = 1; i < 8; ++i) mx = fmaxf(mx, s[i]);
            mx = fmaxf(mx, __shfl_xor(mx, 1));
            mx = fmaxf(mx, __shfl_xor(mx, 2));
            bool need = mx > m_run + THR;
            float m_new = need ? mx : m_run;
            float f = need ? __expf(m_run - m_new) : 1.f;
            float lsum = 0.f;
            bf16x8 pb;
            #pragma unroll
            for (int i = 0; i < 8; ++i) {
                float pv = __expf(s[i] - m_new);
                lsum += pv;
                pb[i] = (__bf16)pv;
            }
            lsum += __shfl_xor(lsum, 1);
            lsum += __shfl_xor(lsum, 2);
            l_run = l_run * f + lsum;
            m_run = m_new;
            *(bf16x8*)&Pl[qo][c8] = pb;
            if ((lane & 3) == 0) fl[qo] = f;
            unsigned long long bal = __ballot(need);
            if (lane == 0) flg[w] = (bal != 0ull) ? 1 : 0;
            // rotate adj pipeline; issue prefetch for tile t+2 (covers ~2 tile-times)
            aA = bA; aB = bB;
            int nxt = (tl + 2 < NT) ? (tl + 2) * KT : 0;
            bA = *(const int4*)(adjp + nxt);
            bB = *(const int4*)(adjp + nxt + 4);
        }
        __syncthreads();   // B2
        // ---- rescale O only when some row's max grew (block-uniform branch) ----
        if (flg[0] | flg[1] | flg[2] | flg[3]) {
            #pragma unroll
            for (int mi = 0; mi < 2; ++mi)
                #pragma unroll
                for (int g = 0; g < 4; ++g) {
                    float4 fv = *(const float4*)&fl[mi * 32 + 8 * g + 4 * hi];
                    #pragma unroll
                    for (int jj = 0; jj < 4; ++jj) {
                        float fac = (&fv.x)[jj];
                        #pragma unroll
                        for (int h = 0; h < 2; ++h)
                            #pragma unroll
                            for (int ni = 0; ni < 2; ++ni)
                                O[h][mi][ni][g * 4 + jj] *= fac;
                    }
                }
        }
        // ---- PV: P frags from LDS, V frags direct (padded stride) ----
        bf16x8 pa[2][2];
        #pragma unroll
        for (int mi = 0; mi < 2; ++mi)
            #pragma unroll
            for (int ks = 0; ks < 2; ++ks)
                pa[mi][ks] = *(const bf16x8*)&Pl[mi * 32 + lo][ks * 16 + hi * 8];
        const int vofs = tl * KT;
        #pragma unroll
        for (int h = 0; h < 2; ++h)
            #pragma unroll
            for (int ni = 0; ni < 2; ++ni) {
                const __bf16* vp = Vbase + (size_t)(h * 64 + ni * 32) * LDV + vofs;
                bf16x8 vb0 = *(const bf16x8*)(vp);
                bf16x8 vb1 = *(const bf16x8*)(vp + 16);
                O[h][0][ni] = mfma(pa[0][0], vb0, O[h][0][ni]);
                O[h][1][ni] = mfma(pa[1][0], vb0, O[h][1][ni]);
                O[h][0][ni] = mfma(pa[0][1], vb1, O[h][0][ni]);
                O[h][1][ni] = mfma(pa[1][1], vb1, O[h][1][ni]);
            }
    }
    // ---- epilogue ----
    if ((lane & 3) == 0) {
        ll[qo] = l_run;
        lse[(size_t)split * NR + qblk + qo] = m_run + __logf(l_run);
    }
    __syncthreads();
    #pragma unroll
    for (int mi = 0; mi < 2; ++mi)
        #pragma unroll
        for (int g = 0; g < 4; ++g) {
            float4 lv = *(const float4*)&ll[mi * 32 + 8 * g + 4 * hi];
            #pragma unroll
            for (int jj = 0; jj < 4; ++jj) {
                float inv = 1.f / (&lv.x)[jj];
                int row = qblk + mi * 32 + 8 * g + 4 * hi + jj;
                #pragma unroll
                for (int h = 0; h < 2; ++h)
                    #pragma unroll
                    for (int ni = 0; ni < 2; ++ni) {
                        int col = w * 128 + h * 64 + ni * 32 + lo;
                        Opart[(size_t)split * NR * DD + (size_t)row * DD + col] =
                            (__bf16)(O[h][mi][ni][g * 4 + jj] * inv);
                    }
            }
        }
}

// ---------------- merge kv-splits ----------------
__global__ void __launch_bounds__(256)
merge_kernel(const __bf16* __restrict__ Opart, const float* __restrict__ lse,
             __bf16* __restrict__ attn)
{
    int idx = blockIdx.x * 256 + threadIdx.x;
    int q = idx >> 6;
    int c = (idx & 63) * 8;
    float l0 = lse[q], l1 = lse[NR + q], l2 = lse[2 * NR + q], l3 = lse[3 * NR + q];
    float M = fmaxf(fmaxf(l0, l1), fmaxf(l2, l3));
    float w0 = __expf(l0 - M), w1 = __expf(l1 - M), w2 = __expf(l2 - M), w3 = __expf(l3 - M);
    float Winv = 1.f / (w0 + w1 + w2 + w3);
    const size_t base = (size_t)q * DD + c;
    const size_t stride = (size_t)NR * DD;
    bf16x8 o0 = *(const bf16x8*)(Opart + base);
    bf16x8 o1 = *(const bf16x8*)(Opart + stride + base);
    bf16x8 o2 = *(const bf16x8*)(Opart + 2 * stride + base);
    bf16x8 o3 = *(const bf16x8*)(Opart + 3 * stride + base);
    bf16x8 o;
    #pragma unroll
    for (int i = 0; i < 8; ++i)
        o[i] = (__bf16)((w0 * (float)o0[i] + w1 * (float)o1[i] +
                         w2 * (float)o2[i] + w3 * (float)o3[i]) * Winv);
    *(bf16x8*)(attn + base) = o;
}

} // namespace

extern "C" void kernel_launch(void* const* d_in, const int* in_sizes, int n_in,
                              void* d_out, int out_size, void* d_ws, size_t ws_size,
                              hipStream_t stream)
{
    (void)in_sizes; (void)n_in; (void)out_size; (void)ws_size;
    const float* X  = (const float*)d_in[0];
    const int*   adj = (const int*)d_in[1];
    const float* Wq = (const float*)d_in[2];
    const float* Wk = (const float*)d_in[3];
    const float* Wv = (const float*)d_in[4];
    const float* Wo = (const float*)d_in[5];
    const float* bo = (const float*)d_in[6];
    float* out = (float*)d_out;

    char* ws = (char*)d_ws;
    // layout (bytes):
    __bf16* Xb   = (__bf16*)(ws + 0);          // 8192x512 bf16  (8.39 MB); Att reuses
    __bf16* Att  = (__bf16*)(ws + 0);
    __bf16* Wqb  = (__bf16*)(ws + 8388608);
    __bf16* Wkb  = (__bf16*)(ws + 8912896);
    __bf16* Wvb  = (__bf16*)(ws + 9437184);
    __bf16* Wob  = (__bf16*)(ws + 9961472);
    __bf16* Qb   = (__bf16*)(ws + 10485760);   // 8192x512      (8.39 MB)
    __bf16* Kp   = (__bf16*)(ws + 18874368);   // 8192xLDK(528) (8.65 MB)
    __bf16* Vtb  = (__bf16*)(ws + 27525120);   // 512xLDV(8208) (8.40 MB)
    __bf16* Vb   = (__bf16*)(ws + 35930112);   // 8192x512      (8.39 MB, dead after transpose)
    __bf16* Op   = (__bf16*)(ws + 35930112);   // 4x8192x512 bf16 (33.5 MB) overlaps dead Vb
    float*  lseb = (float*)(ws + 69484544);    // 4x8192 f32
    // total = 69,615,616 bytes (< previous 77.7 MB high-water)

    cast_kernel<<<2048, 256, 0, stream>>>(X,  Xb,  NR * DD / 8);
    cast_kernel<<<128,  256, 0, stream>>>(Wq, Wqb, DD * DD / 8);
    cast_kernel<<<128,  256, 0, stream>>>(Wk, Wkb, DD * DD / 8);
    cast_kernel<<<128,  256, 0, stream>>>(Wv, Wvb, DD * DD / 8);
    cast_kernel<<<128,  256, 0, stream>>>(Wo, Wob, DD * DD / 8);

    gemm_kernel<false><<<dim3(256, 3), 256, 0, stream>>>(Xb, Wqb, Wkb, Wvb,
                                                         Qb, Kp, Vb, nullptr, nullptr);
    transpose_kernel<<<dim3(128, 8), 256, 0, stream>>>(Vb, Vtb);
    flash_kernel<<<512, 256, 0, stream>>>(Qb, Kp, Vtb, adj, Op, lseb);
    merge_kernel<<<2048, 256, 0, stream>>>(Op, lseb, Att);
    gemm_kernel<true><<<dim3(256, 1), 256, 0, stream>>>(Att, Wob, nullptr, nullptr,
                                                        nullptr, nullptr, nullptr, bo, out);
}